// Round 1
// baseline (3666.703 us; speedup 1.0000x reference)
//
#include <hip/hip_runtime.h>
#include <stdint.h>

// Conductance-LIF network, persistent-kernel event-driven implementation.
//
// Layout: grid = 256 blocks = 32 batches x 8 blocks/batch (b = blockIdx%32 so a
// batch's 8 blocks land on one XCD under round-robin dispatch). Block = 768
// threads = 4 subgroups x 192. Subgroup 0 owns the 192 neurons' LIF/synapse
// state in registers; all subgroups split the per-step spike list 4 ways and
// reduce partial conductance sums through LDS.
//
// Spikes are binary -> matmuls become "sum W rows over spiking set". Synapses
// 0,1 share the ct0 pre-mask => only two recurrent sums (z0, z1) + one FF sum.
// Scaling factors are (pre-ct, post-ct) separable => applied after summation.
//
// Cross-block (same-batch) exchange: write-once recmask/recflag arrays in d_ws,
// agent-scope atomics (per-XCD L2s are not coherent); MAGIC != 0xAAAAAAAA
// poison so no initialization pass is needed. All 256 blocks are co-resident
// under any packing (3072 waves vs 8192 slots) => spin-wait is deadlock-free.

#define MAGIC 0x5EED5EEDu

__global__ __launch_bounds__(768) void snn_lif_kernel(
    const float* __restrict__ I,     // [32][256][768] input spikes (0/1)
    const float* __restrict__ W,     // [1536][1536] recurrent weights (row = pre)
    const float* __restrict__ WF,    // [768][1536]  FF weights (row = input)
    const float* __restrict__ sf,    // [2][2] scaling (pre ct, post ct)
    const float* __restrict__ sfF,   // [1][2] FF scaling (post ct)
    const int*   __restrict__ ct,    // [1536] cell type 0/1
    float* __restrict__ out,         // spk [32][256][1536] then volt [...]
    uint64_t* __restrict__ recmask,  // [32][256][24] spike bit-words
    uint32_t* __restrict__ recflag)  // [32][256][24] publish flags
{
    const int tid = threadIdx.x;
    const int b   = blockIdx.x & 31;   // batch
    const int j   = blockIdx.x >> 5;   // block-in-batch 0..7
    const int sg  = tid / 192;         // subgroup 0..3
    const int lm  = tid - sg * 192;    // neuron-within-block 0..191
    const int m   = j * 192 + lm;      // global neuron id
    const int wv  = tid >> 6;          // wave id 0..11
    const int wl  = tid & 63;          // lane id

    __shared__ uint32_t ent[3840];         // L0:[0,1536) L1:[1536,3072) F:[3072,3840)
    __shared__ float    part[3][3][192];   // partial z from subgroups 1..3
    __shared__ uint32_t totals_sh;         // packed list sizes
    __shared__ uint64_t ctm_sh[24];        // cell-type bitmask
    __shared__ uint64_t fmask_sh[12];      // this-step FF spike mask

    // ---- cell-type bitmask via block-wide ballots (2 x 768 lanes) ----
    for (int r = 0; r < 2; ++r) {
        int c = ct[r * 768 + tid];
        uint64_t bal = __ballot(c != 0);
        if (wl == 0) ctm_sh[r * 12 + wv] = bal;
    }
    __syncthreads();

    // ---- per-owner-neuron constants (subgroup 0 uses them) ----
    const int   myct = ct[m];
    const float s0m  = sf[myct];           // sf[0][ct_m]
    const float s1m  = sf[2 + myct];       // sf[1][ct_m]
    const float sFm  = sfF[myct];
    const float lc   = (myct == 0) ? (1.0f / 200.0f) : (1.0f / 100.0f); // DT/(tau_mem*g_l)
    const float refsteps = (myct == 0) ? 2.0f : 1.0f;
    // synapse filter coefficients, computed exactly as reference does (f32)
    const float ar0 = expf(-1.0f / 0.5f),  ad0 = expf(-1.0f / 2.0f);
    const float ar1 = expf(-1.0f / 2.0f),  ad1 = expf(-1.0f / 100.0f);
    const float ar2 = expf(-1.0f / 0.5f),  ad2 = expf(-1.0f / 5.0f);
    const float arF = expf(-1.0f / 0.5f),  adF = expf(-1.0f / 2.0f);

    // ---- state (subgroup 0 registers) ----
    float U = -65.0f, refc = 0.0f;
    float x0 = 0, g0 = 0, x1 = 0, g1 = 0, x2 = 0, g2 = 0, xF = 0, gF = 0;

    const uint64_t ctw = (wl < 24) ? ctm_sh[wl] : 0ull;  // wave0 scan uses it
    const int btbase = b * 256;

    for (int t = 0; t < 256; ++t) {
        // ---- FF spike mask for this step: block-wide ballot of I[b,t,:] ----
        float iv = I[(uint32_t)(btbase + t) * 768u + (uint32_t)tid];
        uint64_t fb = __ballot(iv > 0.5f);
        if (wl == 0) fmask_sh[wv] = fb;
        __syncthreads();   // (c)

        // ---- phase A (wave 0): wait for siblings' spikes, build entry lists ----
        if (wv == 0) {
            uint64_t sm = 0, fm = 0;
            uint32_t c0 = 0, c1 = 0, cF = 0;
            if (wl < 24) {
                if (t > 0) {
                    const uint32_t fi = (uint32_t)(btbase + t - 1) * 24u + (uint32_t)wl;
                    while (__hip_atomic_load(&recflag[fi], __ATOMIC_ACQUIRE,
                                             __HIP_MEMORY_SCOPE_AGENT) != MAGIC) { }
                    sm = __hip_atomic_load(&recmask[fi], __ATOMIC_RELAXED,
                                           __HIP_MEMORY_SCOPE_AGENT);
                }
                c0 = __popcll(sm & ~ctw);
                c1 = __popcll(sm & ctw);
            } else if (wl < 36) {
                fm = fmask_sh[wl - 24];
                cF = __popcll(fm);
            }
            // packed 3-list exclusive scan across the wave (11/11/10 bits)
            uint32_t pack = c0 | (c1 << 11) | (cF << 22);
            uint32_t incl = pack;
            #pragma unroll
            for (int d = 1; d < 64; d <<= 1) {
                uint32_t u = __shfl_up(incl, d, 64);
                if (wl >= d) incl += u;
            }
            const uint32_t excl = incl - pack;
            if (wl == 35) totals_sh = incl;   // lane35 inclusive = all totals
            uint32_t p0 = excl & 0x7FFu;
            uint32_t p1 = 1536u + ((excl >> 11) & 0x7FFu);
            uint32_t pF = 3072u + (excl >> 22);
            if (wl < 24) {
                uint64_t mm = sm;
                const uint32_t lanebase = (uint32_t)wl * 64u * 1536u;
                while (mm) {
                    const int bit = __builtin_ctzll(mm);
                    mm &= mm - 1;
                    const uint32_t off = lanebase + (uint32_t)bit * 1536u; // n*N elem offset
                    if ((ctw >> bit) & 1ull) ent[p1++] = off;
                    else                     ent[p0++] = off;
                }
            } else if (wl < 36) {
                uint64_t mm = fm;
                const uint32_t lanebase = (uint32_t)(wl - 24) * 64u * 1536u;
                while (mm) {
                    const int bit = __builtin_ctzll(mm);
                    mm &= mm - 1;
                    ent[pF++] = lanebase + (uint32_t)bit * 1536u;
                }
            }
        }
        __syncthreads();   // (b)

        // ---- phase B (all threads): 4-way-split row accumulation ----
        const uint32_t tp = totals_sh;
        const uint32_t t0 = tp & 0x7FFu;
        const uint32_t t1 = (tp >> 11) & 0x7FFu;
        const uint32_t tF = tp >> 22;
        float z0 = 0.f, z1 = 0.f, zF = 0.f;
        {
            uint32_t s_ = (t0 * (uint32_t)sg) >> 2, e_ = (t0 * (uint32_t)(sg + 1)) >> 2;
            #pragma unroll 4
            for (uint32_t i = s_; i < e_; ++i) z0 += W[ent[i] + (uint32_t)m];
            s_ = (t1 * (uint32_t)sg) >> 2; e_ = (t1 * (uint32_t)(sg + 1)) >> 2;
            #pragma unroll 4
            for (uint32_t i = s_; i < e_; ++i) z1 += W[ent[1536u + i] + (uint32_t)m];
            s_ = (tF * (uint32_t)sg) >> 2; e_ = (tF * (uint32_t)(sg + 1)) >> 2;
            #pragma unroll 4
            for (uint32_t i = s_; i < e_; ++i) zF += WF[ent[3072u + i] + (uint32_t)m];
        }
        if (sg != 0) {
            part[sg - 1][0][lm] = z0;
            part[sg - 1][1][lm] = z1;
            part[sg - 1][2][lm] = zF;
        }
        __syncthreads();   // (a)

        // ---- phase C (subgroup 0): reduce, LIF update, publish spikes ----
        if (sg == 0) {
            z0 += part[0][0][lm]; z0 += part[1][0][lm]; z0 += part[2][0][lm];
            z1 += part[0][1][lm]; z1 += part[1][1][lm]; z1 += part[2][1][lm];
            zF += part[0][2][lm]; zF += part[1][2][lm]; zF += part[2][2][lm];
            z0 *= s0m; z1 *= s1m; zF *= sFm;
            x0 = ar0 * x0 + z0;  g0 = ad0 * g0 + x0;   // syn0 (pre ct0)
            x1 = ar1 * x1 + z0;  g1 = ad1 * g1 + x1;   // syn1 (pre ct0, same z0)
            x2 = ar2 * x2 + z1;  g2 = ad2 * g2 + x2;   // syn2 (pre ct1)
            xF = arF * xF + zF;  gF = adF * gF + xF;   // feed-forward
            const float gtot = g0 + 0.5f * g1 + g2 + gF;     // gbar = [1, .5, 1], FF 1
            const float gE   = -70.0f * g2;                  // gbar*Erev = [0,0,-70], FF Erev=0
            const float Isyn = gE - gtot * U;
            float Un = U + lc * (10.0f * (-65.0f - U) + Isyn);
            if (refc > 0.0f) Un = -65.0f;                    // refractory clamp (pre-decrement)
            refc = fmaxf(refc - 1.0f, 0.0f);
            const bool s = (Un - (-50.0f)) >= 0.0f;          // spike(U_new - theta)
            const float Uo = s ? -65.0f : Un;
            refc = s ? refsteps : refc;
            U = Uo;
            const uint32_t oidx = (uint32_t)(btbase + t) * 1536u + (uint32_t)m;
            out[oidx] = s ? 1.0f : 0.0f;
            out[12582912u + oidx] = Uo;                      // volts after spikes
            const uint64_t bal = __ballot(s);                // wave covers 64 consecutive m
            if (wl == 0) {
                const uint32_t widx = (uint32_t)(btbase + t) * 24u + (uint32_t)(j * 3 + wv);
                __hip_atomic_store(&recmask[widx], bal, __ATOMIC_RELAXED,
                                   __HIP_MEMORY_SCOPE_AGENT);
                __hip_atomic_store(&recflag[widx], MAGIC, __ATOMIC_RELEASE,
                                   __HIP_MEMORY_SCOPE_AGENT);
            }
        }
    }
}

extern "C" void kernel_launch(void* const* d_in, const int* in_sizes, int n_in,
                              void* d_out, int out_size, void* d_ws, size_t ws_size,
                              hipStream_t stream) {
    const float* I   = (const float*)d_in[0];   // input_spikes (32,256,768)
    const float* W   = (const float*)d_in[1];   // weights (1536,1536)
    const float* WF  = (const float*)d_in[2];   // weights_FF (768,1536)
    const float* sf  = (const float*)d_in[3];   // scaling_factors (2,2)
    const float* sfF = (const float*)d_in[4];   // scaling_factors_FF (1,2)
    const int*   ct  = (const int*)d_in[5];     // cell_type_indices (1536)
    // d_in[6] cell_type_indices_FF: all zeros, folded into sfF indexing.

    uint8_t* ws = (uint8_t*)d_ws;
    uint64_t* recmask = (uint64_t*)ws;                       // 32*256*24*8 = 1,572,864 B
    uint32_t* recflag = (uint32_t*)(ws + 32 * 256 * 24 * 8); // +786,432 B (ws >= 2.25 MiB)

    snn_lif_kernel<<<dim3(256), dim3(768), 0, stream>>>(
        I, W, WF, sf, sfF, ct, (float*)d_out, recmask, recflag);
}